// Round 1
// baseline (1836.990 us; speedup 1.0000x reference)
//
#include <hip/hip_runtime.h>

#define IN_F 64
#define OUT_F 64

// ---------------------------------------------------------------------------
// Edge scatter: msg = feat[src] * e_feat  ->  atomicAdd into neigh[dst]
// 16 threads per edge, each handles one float4 (4 feats).
// ---------------------------------------------------------------------------
__global__ __launch_bounds__(256) void edge_scatter_kernel(
    const float* __restrict__ feat, const float* __restrict__ e_feat,
    const int* __restrict__ src, const int* __restrict__ dst,
    float* __restrict__ neigh, int* __restrict__ deg, int nE)
{
    int t = blockIdx.x * blockDim.x + threadIdx.x;
    int e = t >> 4;
    if (e >= nE) return;
    int sub = t & 15;

    int s = src[e];
    int d = dst[e];
    float w = e_feat[e];

    const float4 v = *reinterpret_cast<const float4*>(feat + (size_t)s * IN_F + sub * 4);
    float* p = neigh + (size_t)d * IN_F + sub * 4;
    atomicAdd(p + 0, v.x * w);
    atomicAdd(p + 1, v.y * w);
    atomicAdd(p + 2, v.z * w);
    atomicAdd(p + 3, v.w * w);
    if (sub == 0) atomicAdd(deg + d, 1);
}

// ---------------------------------------------------------------------------
// Node kernel: h_neigh = neigh_sum / max(deg,1);
//   out = feat @ Ws^T + h_neigh @ Wn^T + (b_self + b_neigh)
// One wave (64 lanes) per node; lane = output feature index.
// W matrices staged transposed in LDS: Wt[i][o] -> lane-consecutive reads
// (2 lanes/bank, conflict-free). Row values broadcast via same-address LDS
// reads (free broadcast). In-place: neigh_sum lives in `out`, each row is
// read+written only by its own wave.
// ---------------------------------------------------------------------------
__global__ __launch_bounds__(256) void node_kernel(
    const float* __restrict__ feat,
    const float* __restrict__ W_self, const float* __restrict__ b_self,
    const float* __restrict__ W_neigh, const float* __restrict__ b_neigh,
    const int* __restrict__ deg,
    float* __restrict__ out, int nN)
{
    __shared__ float Ws[IN_F * OUT_F];   // transposed: Ws[i*64 + o] = W_self[o][i]
    __shared__ float Wn[IN_F * OUT_F];
    __shared__ float frow[4][IN_F];
    __shared__ float hrow[4][IN_F];

    int tid = threadIdx.x;
    for (int idx = tid; idx < IN_F * OUT_F; idx += 256) {
        int o = idx >> 6, i = idx & 63;
        Ws[i * OUT_F + o] = W_self[idx];
        Wn[i * OUT_F + o] = W_neigh[idx];
    }
    __syncthreads();

    int wave = tid >> 6;
    int lane = tid & 63;
    int n = blockIdx.x * 4 + wave;
    if (n >= nN) return;

    // stage this node's feat row and h_neigh row (wave-synchronous LDS use)
    float f  = feat[(size_t)n * IN_F + lane];
    float ns = out[(size_t)n * IN_F + lane];
    float invd = 1.0f / (float)max(deg[n], 1);
    frow[wave][lane] = f;
    hrow[wave][lane] = ns * invd;
    __builtin_amdgcn_s_waitcnt(0);   // drain lgkmcnt: wave-lockstep makes this safe

    float acc = b_self[lane] + b_neigh[lane];
    #pragma unroll
    for (int i = 0; i < IN_F; ++i) {
        acc = fmaf(frow[wave][i], Ws[i * OUT_F + lane], acc);
        acc = fmaf(hrow[wave][i], Wn[i * OUT_F + lane], acc);
    }
    out[(size_t)n * IN_F + lane] = acc;
}

extern "C" void kernel_launch(void* const* d_in, const int* in_sizes, int n_in,
                              void* d_out, int out_size, void* d_ws, size_t ws_size,
                              hipStream_t stream) {
    const float* feat    = (const float*)d_in[0];
    const float* e_feat  = (const float*)d_in[1];
    const int*   src     = (const int*)d_in[2];
    const int*   dst     = (const int*)d_in[3];
    const float* W_self  = (const float*)d_in[4];
    const float* b_self  = (const float*)d_in[5];
    const float* W_neigh = (const float*)d_in[6];
    const float* b_neigh = (const float*)d_in[7];

    int nN = in_sizes[0] / IN_F;    // 100000
    int nE = in_sizes[2];           // 1600000

    float* out = (float*)d_out;     // doubles as neigh_sum accumulator
    int*   deg = (int*)d_ws;        // nN ints

    // zero accumulators (harness does not re-poison between replays)
    hipMemsetAsync(out, 0, (size_t)nN * OUT_F * sizeof(float), stream);
    hipMemsetAsync(deg, 0, (size_t)nN * sizeof(int), stream);

    // edge scatter: 16 threads/edge
    {
        long long threads = (long long)nE * 16;
        int blocks = (int)((threads + 255) / 256);
        edge_scatter_kernel<<<blocks, 256, 0, stream>>>(feat, e_feat, src, dst,
                                                        out, deg, nE);
    }

    // node phase: 4 nodes per 256-thread block
    {
        int blocks = (nN + 3) / 4;
        node_kernel<<<blocks, 256, 0, stream>>>(feat, W_self, b_self,
                                                W_neigh, b_neigh, deg, out, nN);
    }
}

// Round 2
// 802.510 us; speedup vs baseline: 2.2891x; 2.2891x over previous
//
#include <hip/hip_runtime.h>

#define IN_F 64
#define OUT_F 64

// ===========================================================================
// CSR-build path: counting sort by dst, then per-node gather (no fp atomics).
// ===========================================================================

// K1: degree histogram into cnt[] (pre-zeroed)
__global__ __launch_bounds__(256) void deg_hist_kernel(
    const int* __restrict__ dst, int* __restrict__ cnt, int nE)
{
    int e = blockIdx.x * blockDim.x + threadIdx.x;
    if (e < nE) atomicAdd(cnt + dst[e], 1);
}

// K2: single-block in-place exclusive scan of cnt[0..nN)
__global__ __launch_bounds__(1024) void scan_kernel(int* __restrict__ c, int nN)
{
    __shared__ int part[1024];
    int t = threadIdx.x;
    int chunk = (nN + 1023) >> 10;
    int lo = min(t * chunk, nN);
    int hi = min(lo + chunk, nN);
    int s = 0;
    for (int i = lo; i < hi; ++i) s += c[i];
    part[t] = s;
    __syncthreads();
    for (int off = 1; off < 1024; off <<= 1) {
        int v = (t >= off) ? part[t - off] : 0;
        __syncthreads();
        part[t] += v;
        __syncthreads();
    }
    int run = (t > 0) ? part[t - 1] : 0;   // exclusive prefix of this chunk
    for (int i = lo; i < hi; ++i) { int v = c[i]; c[i] = run; run += v; }
}

// K3: scatter edges into CSR slots; cursor starts as exclusive offsets and
// ends as inclusive ends (cursor[n] == offs[n+1]).
__global__ __launch_bounds__(256) void scatter_kernel(
    const int* __restrict__ src, const int* __restrict__ dst,
    const float* __restrict__ ef, int* __restrict__ cursor,
    int2* __restrict__ csr, int nE)
{
    int e = blockIdx.x * blockDim.x + threadIdx.x;
    if (e >= nE) return;
    int d = dst[e];
    int pos = atomicAdd(cursor + d, 1);
    csr[pos] = make_int2(src[e], __float_as_int(ef[e]));
}

// K4: per-node gather-accumulate + fused dual GEMV epilogue.
// One wave per node; lane = feature index. Edge (src,w) pairs prefetched
// 64-wide into LDS per chunk to break the scalar dependent-load chain.
__global__ __launch_bounds__(256) void node_fused_kernel(
    const float* __restrict__ feat, const int2* __restrict__ csr,
    const int* __restrict__ cursor,
    const float* __restrict__ W_self, const float* __restrict__ b_self,
    const float* __restrict__ W_neigh, const float* __restrict__ b_neigh,
    float* __restrict__ out, int nN)
{
    __shared__ float Ws[IN_F * OUT_F];   // transposed: Ws[i*64+o] = W_self[o][i]
    __shared__ float Wn[IN_F * OUT_F];
    __shared__ float frow[4][IN_F];
    __shared__ float hrow[4][IN_F];
    __shared__ int   sbuf[4][64];
    __shared__ float wbuf[4][64];

    int tid = threadIdx.x;
    for (int idx = tid; idx < IN_F * OUT_F; idx += 256) {
        int o = idx >> 6, i = idx & 63;
        Ws[i * OUT_F + o] = W_self[idx];
        Wn[i * OUT_F + o] = W_neigh[idx];
    }
    __syncthreads();

    int wave = tid >> 6;
    int lane = tid & 63;
    int n = blockIdx.x * 4 + wave;
    if (n >= nN) return;

    int start = (n == 0) ? 0 : cursor[n - 1];
    int end   = cursor[n];

    float acc = 0.0f;
    for (int base = start; base < end; base += 64) {
        int cnt = min(64, end - base);
        if (lane < cnt) {
            int2 p = csr[base + lane];
            sbuf[wave][lane] = p.x;
            wbuf[wave][lane] = __int_as_float(p.y);
        }
        __builtin_amdgcn_s_waitcnt(0);   // wave-synchronous LDS publish
        for (int j = 0; j < cnt; ++j) {
            int   s = sbuf[wave][j];     // same-address read -> broadcast
            float w = wbuf[wave][j];
            acc = fmaf(feat[(size_t)s * IN_F + lane], w, acc);
        }
        __builtin_amdgcn_s_waitcnt(0);
    }
    int   degn = end - start;
    float h    = acc / (float)max(degn, 1);

    float f = feat[(size_t)n * IN_F + lane];
    frow[wave][lane] = f;
    hrow[wave][lane] = h;
    __builtin_amdgcn_s_waitcnt(0);

    float r = b_self[lane] + b_neigh[lane];
    #pragma unroll
    for (int i = 0; i < IN_F; ++i) {
        r = fmaf(frow[wave][i], Ws[i * OUT_F + lane], r);
        r = fmaf(hrow[wave][i], Wn[i * OUT_F + lane], r);
    }
    out[(size_t)n * IN_F + lane] = r;
}

// ===========================================================================
// Fallback path (atomic scatter) — used only if ws_size is too small.
// ===========================================================================
__global__ __launch_bounds__(256) void edge_scatter_kernel(
    const float* __restrict__ feat, const float* __restrict__ e_feat,
    const int* __restrict__ src, const int* __restrict__ dst,
    float* __restrict__ neigh, int* __restrict__ deg, int nE)
{
    int t = blockIdx.x * blockDim.x + threadIdx.x;
    int e = t >> 4;
    if (e >= nE) return;
    int sub = t & 15;
    int s = src[e], d = dst[e];
    float w = e_feat[e];
    const float4 v = *reinterpret_cast<const float4*>(feat + (size_t)s * IN_F + sub * 4);
    float* p = neigh + (size_t)d * IN_F + sub * 4;
    atomicAdd(p + 0, v.x * w);
    atomicAdd(p + 1, v.y * w);
    atomicAdd(p + 2, v.z * w);
    atomicAdd(p + 3, v.w * w);
    if (sub == 0) atomicAdd(deg + d, 1);
}

__global__ __launch_bounds__(256) void node_kernel(
    const float* __restrict__ feat,
    const float* __restrict__ W_self, const float* __restrict__ b_self,
    const float* __restrict__ W_neigh, const float* __restrict__ b_neigh,
    const int* __restrict__ deg,
    float* __restrict__ out, int nN)
{
    __shared__ float Ws[IN_F * OUT_F];
    __shared__ float Wn[IN_F * OUT_F];
    __shared__ float frow[4][IN_F];
    __shared__ float hrow[4][IN_F];
    int tid = threadIdx.x;
    for (int idx = tid; idx < IN_F * OUT_F; idx += 256) {
        int o = idx >> 6, i = idx & 63;
        Ws[i * OUT_F + o] = W_self[idx];
        Wn[i * OUT_F + o] = W_neigh[idx];
    }
    __syncthreads();
    int wave = tid >> 6, lane = tid & 63;
    int n = blockIdx.x * 4 + wave;
    if (n >= nN) return;
    float f  = feat[(size_t)n * IN_F + lane];
    float ns = out[(size_t)n * IN_F + lane];
    float invd = 1.0f / (float)max(deg[n], 1);
    frow[wave][lane] = f;
    hrow[wave][lane] = ns * invd;
    __builtin_amdgcn_s_waitcnt(0);
    float acc = b_self[lane] + b_neigh[lane];
    #pragma unroll
    for (int i = 0; i < IN_F; ++i) {
        acc = fmaf(frow[wave][i], Ws[i * OUT_F + lane], acc);
        acc = fmaf(hrow[wave][i], Wn[i * OUT_F + lane], acc);
    }
    out[(size_t)n * IN_F + lane] = acc;
}

extern "C" void kernel_launch(void* const* d_in, const int* in_sizes, int n_in,
                              void* d_out, int out_size, void* d_ws, size_t ws_size,
                              hipStream_t stream) {
    const float* feat    = (const float*)d_in[0];
    const float* e_feat  = (const float*)d_in[1];
    const int*   src     = (const int*)d_in[2];
    const int*   dst     = (const int*)d_in[3];
    const float* W_self  = (const float*)d_in[4];
    const float* b_self  = (const float*)d_in[5];
    const float* W_neigh = (const float*)d_in[6];
    const float* b_neigh = (const float*)d_in[7];

    int nN = in_sizes[0] / IN_F;    // 100000
    int nE = in_sizes[2];           // 1600000

    float* out = (float*)d_out;

    size_t cursor_bytes = ((size_t)nN * sizeof(int) + 15) & ~(size_t)15;
    size_t need = cursor_bytes + (size_t)nE * sizeof(int2);

    if (ws_size >= need) {
        // ---- CSR path ----
        int*  cursor = (int*)d_ws;
        int2* csr    = (int2*)((char*)d_ws + cursor_bytes);

        hipMemsetAsync(cursor, 0, (size_t)nN * sizeof(int), stream);
        deg_hist_kernel<<<(nE + 255) / 256, 256, 0, stream>>>(dst, cursor, nE);
        scan_kernel<<<1, 1024, 0, stream>>>(cursor, nN);
        scatter_kernel<<<(nE + 255) / 256, 256, 0, stream>>>(src, dst, e_feat,
                                                             cursor, csr, nE);
        node_fused_kernel<<<(nN + 3) / 4, 256, 0, stream>>>(
            feat, csr, cursor, W_self, b_self, W_neigh, b_neigh, out, nN);
    } else {
        // ---- fallback atomic path ----
        int* deg = (int*)d_ws;
        hipMemsetAsync(out, 0, (size_t)nN * OUT_F * sizeof(float), stream);
        hipMemsetAsync(deg, 0, (size_t)nN * sizeof(int), stream);
        long long threads = (long long)nE * 16;
        edge_scatter_kernel<<<(int)((threads + 255) / 256), 256, 0, stream>>>(
            feat, e_feat, src, dst, out, deg, nE);
        node_kernel<<<(nN + 3) / 4, 256, 0, stream>>>(
            feat, W_self, b_self, W_neigh, b_neigh, deg, out, nN);
    }
}

// Round 3
// 338.485 us; speedup vs baseline: 5.4271x; 2.3709x over previous
//
#include <hip/hip_runtime.h>

#define IN_F 64
#define OUT_F 64
#define WPAD 65   // padded LDS stride: banks (i+lane)%32 -> 2-way aliasing = free

// ===========================================================================
// CSR-build path: counting sort by dst, then per-node gather (no fp atomics).
// ===========================================================================

// K1: degree histogram into cnt[] (pre-zeroed)
__global__ __launch_bounds__(256) void deg_hist_kernel(
    const int* __restrict__ dst, int* __restrict__ cnt, int nE)
{
    int e = blockIdx.x * blockDim.x + threadIdx.x;
    if (e < nE) atomicAdd(cnt + dst[e], 1);
}

// K2a: per-block exclusive scan (1024 elems/block), block totals -> partials
__global__ __launch_bounds__(1024) void scan_block_kernel(
    int* __restrict__ c, int* __restrict__ partials, int nN)
{
    __shared__ int buf[1024];
    int t = threadIdx.x;
    int gid = blockIdx.x * 1024 + t;
    int v = (gid < nN) ? c[gid] : 0;
    buf[t] = v;
    __syncthreads();
    for (int off = 1; off < 1024; off <<= 1) {
        int u = (t >= off) ? buf[t - off] : 0;
        __syncthreads();
        buf[t] += u;
        __syncthreads();
    }
    if (gid < nN) c[gid] = buf[t] - v;            // exclusive
    if (t == 1023) partials[blockIdx.x] = buf[t]; // inclusive block total
}

// K2b: single-block exclusive scan of partials (nP <= 1024)
__global__ __launch_bounds__(1024) void scan_partials_kernel(
    int* __restrict__ p, int nP)
{
    __shared__ int buf[1024];
    int t = threadIdx.x;
    int v = (t < nP) ? p[t] : 0;
    buf[t] = v;
    __syncthreads();
    for (int off = 1; off < 1024; off <<= 1) {
        int u = (t >= off) ? buf[t - off] : 0;
        __syncthreads();
        buf[t] += u;
        __syncthreads();
    }
    if (t < nP) p[t] = buf[t] - v;
}

// K2c: add scanned block offsets back
__global__ __launch_bounds__(1024) void scan_add_kernel(
    int* __restrict__ c, const int* __restrict__ p, int nN)
{
    int gid = blockIdx.x * 1024 + threadIdx.x;
    if (gid < nN) c[gid] += p[blockIdx.x];
}

// K3: scatter edges into CSR slots; cursor ends as inclusive ends.
__global__ __launch_bounds__(256) void scatter_kernel(
    const int* __restrict__ src, const int* __restrict__ dst,
    const float* __restrict__ ef, int* __restrict__ cursor,
    int2* __restrict__ csr, int nE)
{
    int e = blockIdx.x * blockDim.x + threadIdx.x;
    if (e >= nE) return;
    int d = dst[e];
    int pos = atomicAdd(cursor + d, 1);
    csr[pos] = make_int2(src[e], __float_as_int(ef[e]));
}

// K4: per-node gather-accumulate + fused dual GEMV epilogue.
// 512 threads = 8 waves = 8 nodes/block. Lane split: 4 groups x 16 lanes;
// group g owns every-4th edge and gathers float4 (16B/lane) -> 4 independent
// loads in flight per superstep of 16 edges. Cross-group combine: shfl_xor.
__global__ __launch_bounds__(512) void node_fused_kernel(
    const float* __restrict__ feat, const int2* __restrict__ csr,
    const int* __restrict__ cursor,
    const float* __restrict__ W_self, const float* __restrict__ b_self,
    const float* __restrict__ W_neigh, const float* __restrict__ b_neigh,
    float* __restrict__ out, int nN)
{
    __shared__ float Ws[IN_F * WPAD];   // Ws[i*WPAD+o] = W_self[o][i]
    __shared__ float Wn[IN_F * WPAD];
    __shared__ int2  rec[8][64];
    __shared__ float frow[8][IN_F];
    __shared__ float hrow[8][IN_F];

    int tid = threadIdx.x;
    // transposed staging, conflict-free: write banks (lane+o)%32, read coalesced
    for (int idx = tid; idx < IN_F * OUT_F; idx += 512) {
        int o = idx >> 6, i = idx & 63;        // i == lane within the wave
        Ws[i * WPAD + o] = W_self[o * IN_F + i];
        Wn[i * WPAD + o] = W_neigh[o * IN_F + i];
    }
    __syncthreads();

    int wave = tid >> 6;
    int lane = tid & 63;
    int n = blockIdx.x * 8 + wave;
    if (n >= nN) return;

    int start = (n == 0) ? 0 : cursor[n - 1];
    int end   = cursor[n];

    int g   = lane >> 4;    // edge group 0..3
    int sub = lane & 15;    // float4 slot: features 4*sub .. 4*sub+3
    float ax = 0.f, ay = 0.f, az = 0.f, aw = 0.f;

    for (int base = start; base < end; base += 64) {
        int cnt = min(64, end - base);
        __builtin_amdgcn_s_waitcnt(0);          // prior reads done before overwrite
        __builtin_amdgcn_wave_barrier();
        if (lane < cnt) rec[wave][lane] = csr[base + lane];
        __builtin_amdgcn_s_waitcnt(0);          // wave-synchronous LDS publish
        __builtin_amdgcn_wave_barrier();

        int j = 0;
        for (; j + 16 <= cnt; j += 16) {        // superstep: 16 edges, 4 loads/lane
            int2 p0 = rec[wave][j + g];
            int2 p1 = rec[wave][j + 4 + g];
            int2 p2 = rec[wave][j + 8 + g];
            int2 p3 = rec[wave][j + 12 + g];
            const float4 v0 = *reinterpret_cast<const float4*>(feat + (size_t)p0.x * IN_F + sub * 4);
            const float4 v1 = *reinterpret_cast<const float4*>(feat + (size_t)p1.x * IN_F + sub * 4);
            const float4 v2 = *reinterpret_cast<const float4*>(feat + (size_t)p2.x * IN_F + sub * 4);
            const float4 v3 = *reinterpret_cast<const float4*>(feat + (size_t)p3.x * IN_F + sub * 4);
            float w0 = __int_as_float(p0.y), w1 = __int_as_float(p1.y);
            float w2 = __int_as_float(p2.y), w3 = __int_as_float(p3.y);
            ax = fmaf(v0.x, w0, ax); ay = fmaf(v0.y, w0, ay);
            az = fmaf(v0.z, w0, az); aw = fmaf(v0.w, w0, aw);
            ax = fmaf(v1.x, w1, ax); ay = fmaf(v1.y, w1, ay);
            az = fmaf(v1.z, w1, az); aw = fmaf(v1.w, w1, aw);
            ax = fmaf(v2.x, w2, ax); ay = fmaf(v2.y, w2, ay);
            az = fmaf(v2.z, w2, az); aw = fmaf(v2.w, w2, aw);
            ax = fmaf(v3.x, w3, ax); ay = fmaf(v3.y, w3, ay);
            az = fmaf(v3.z, w3, az); aw = fmaf(v3.w, w3, aw);
        }
        for (; j < cnt; j += 4) {               // tail: up to 4 edges at a time
            int jj = j + g;
            if (jj < cnt) {
                int2 p = rec[wave][jj];
                const float4 v = *reinterpret_cast<const float4*>(feat + (size_t)p.x * IN_F + sub * 4);
                float w = __int_as_float(p.y);
                ax = fmaf(v.x, w, ax); ay = fmaf(v.y, w, ay);
                az = fmaf(v.z, w, az); aw = fmaf(v.w, w, aw);
            }
        }
    }

    // combine the 4 edge-groups: lanes {sub, sub+16, sub+32, sub+48}
    ax += __shfl_xor(ax, 16); ax += __shfl_xor(ax, 32);
    ay += __shfl_xor(ay, 16); ay += __shfl_xor(ay, 32);
    az += __shfl_xor(az, 16); az += __shfl_xor(az, 32);
    aw += __shfl_xor(aw, 16); aw += __shfl_xor(aw, 32);

    int   degn = end - start;
    float invd = 1.0f / (float)max(degn, 1);
    __builtin_amdgcn_wave_barrier();
    if (lane < 16) {
        float4 hv = make_float4(ax * invd, ay * invd, az * invd, aw * invd);
        *reinterpret_cast<float4*>(&hrow[wave][sub * 4]) = hv;
    }
    frow[wave][lane] = feat[(size_t)n * IN_F + lane];
    __builtin_amdgcn_s_waitcnt(0);
    __builtin_amdgcn_wave_barrier();

    float r = b_self[lane] + b_neigh[lane];
    #pragma unroll
    for (int i = 0; i < IN_F; ++i) {
        r = fmaf(frow[wave][i], Ws[i * WPAD + lane], r);
        r = fmaf(hrow[wave][i], Wn[i * WPAD + lane], r);
    }
    out[(size_t)n * IN_F + lane] = r;
}

// ===========================================================================
// Fallback path (atomic scatter) — used only if ws_size is too small.
// ===========================================================================
__global__ __launch_bounds__(256) void edge_scatter_kernel(
    const float* __restrict__ feat, const float* __restrict__ e_feat,
    const int* __restrict__ src, const int* __restrict__ dst,
    float* __restrict__ neigh, int* __restrict__ deg, int nE)
{
    int t = blockIdx.x * blockDim.x + threadIdx.x;
    int e = t >> 4;
    if (e >= nE) return;
    int sub = t & 15;
    int s = src[e], d = dst[e];
    float w = e_feat[e];
    const float4 v = *reinterpret_cast<const float4*>(feat + (size_t)s * IN_F + sub * 4);
    float* p = neigh + (size_t)d * IN_F + sub * 4;
    atomicAdd(p + 0, v.x * w);
    atomicAdd(p + 1, v.y * w);
    atomicAdd(p + 2, v.z * w);
    atomicAdd(p + 3, v.w * w);
    if (sub == 0) atomicAdd(deg + d, 1);
}

__global__ __launch_bounds__(256) void node_kernel(
    const float* __restrict__ feat,
    const float* __restrict__ W_self, const float* __restrict__ b_self,
    const float* __restrict__ W_neigh, const float* __restrict__ b_neigh,
    const int* __restrict__ deg,
    float* __restrict__ out, int nN)
{
    __shared__ float Ws[IN_F * WPAD];
    __shared__ float Wn[IN_F * WPAD];
    __shared__ float frow[4][IN_F];
    __shared__ float hrow[4][IN_F];
    int tid = threadIdx.x;
    for (int idx = tid; idx < IN_F * OUT_F; idx += 256) {
        int o = idx >> 6, i = idx & 63;
        Ws[i * WPAD + o] = W_self[o * IN_F + i];
        Wn[i * WPAD + o] = W_neigh[o * IN_F + i];
    }
    __syncthreads();
    int wave = tid >> 6, lane = tid & 63;
    int n = blockIdx.x * 4 + wave;
    if (n >= nN) return;
    float f  = feat[(size_t)n * IN_F + lane];
    float ns = out[(size_t)n * IN_F + lane];
    float invd = 1.0f / (float)max(deg[n], 1);
    frow[wave][lane] = f;
    hrow[wave][lane] = ns * invd;
    __builtin_amdgcn_s_waitcnt(0);
    __builtin_amdgcn_wave_barrier();
    float acc = b_self[lane] + b_neigh[lane];
    #pragma unroll
    for (int i = 0; i < IN_F; ++i) {
        acc = fmaf(frow[wave][i], Ws[i * WPAD + lane], acc);
        acc = fmaf(hrow[wave][i], Wn[i * WPAD + lane], acc);
    }
    out[(size_t)n * IN_F + lane] = acc;
}

extern "C" void kernel_launch(void* const* d_in, const int* in_sizes, int n_in,
                              void* d_out, int out_size, void* d_ws, size_t ws_size,
                              hipStream_t stream) {
    const float* feat    = (const float*)d_in[0];
    const float* e_feat  = (const float*)d_in[1];
    const int*   src     = (const int*)d_in[2];
    const int*   dst     = (const int*)d_in[3];
    const float* W_self  = (const float*)d_in[4];
    const float* b_self  = (const float*)d_in[5];
    const float* W_neigh = (const float*)d_in[6];
    const float* b_neigh = (const float*)d_in[7];

    int nN = in_sizes[0] / IN_F;    // 100000
    int nE = in_sizes[2];           // 1600000

    float* out = (float*)d_out;

    size_t cursor_bytes = ((size_t)nN * sizeof(int) + 15) & ~(size_t)15;
    size_t need = cursor_bytes + (size_t)nE * sizeof(int2);

    if (ws_size >= need) {
        // ---- CSR path ----
        int*  cursor   = (int*)d_ws;
        int2* csr      = (int2*)((char*)d_ws + cursor_bytes);
        int*  partials = (int*)csr;   // alias: used only BEFORE csr is written

        int nB = (nN + 1023) / 1024;  // 98 <= 1024

        hipMemsetAsync(cursor, 0, (size_t)nN * sizeof(int), stream);
        deg_hist_kernel<<<(nE + 255) / 256, 256, 0, stream>>>(dst, cursor, nE);
        scan_block_kernel<<<nB, 1024, 0, stream>>>(cursor, partials, nN);
        scan_partials_kernel<<<1, 1024, 0, stream>>>(partials, nB);
        scan_add_kernel<<<nB, 1024, 0, stream>>>(cursor, partials, nN);
        scatter_kernel<<<(nE + 255) / 256, 256, 0, stream>>>(src, dst, e_feat,
                                                             cursor, csr, nE);
        node_fused_kernel<<<(nN + 7) / 8, 512, 0, stream>>>(
            feat, csr, cursor, W_self, b_self, W_neigh, b_neigh, out, nN);
    } else {
        // ---- fallback atomic path ----
        int* deg = (int*)d_ws;
        hipMemsetAsync(out, 0, (size_t)nN * OUT_F * sizeof(float), stream);
        hipMemsetAsync(deg, 0, (size_t)nN * sizeof(int), stream);
        long long threads = (long long)nE * 16;
        edge_scatter_kernel<<<(int)((threads + 255) / 256), 256, 0, stream>>>(
            feat, e_feat, src, dst, out, deg, nE);
        node_kernel<<<(nN + 3) / 4, 256, 0, stream>>>(
            feat, W_self, b_self, W_neigh, b_neigh, deg, out, nN);
    }
}